// Round 1
// baseline (6066.850 us; speedup 1.0000x reference)
//
#include <hip/hip_runtime.h>
#include <stdint.h>

#define NN 60000
#define NE 1920000

typedef float f32x4 __attribute__((ext_vector_type(4)));
typedef short s16x8 __attribute__((ext_vector_type(8)));

__device__ __forceinline__ uint16_t f2bf(float f) {
  union { float f; uint32_t u; } v; v.f = f;
  uint32_t r = v.u + 0x7FFFu + ((v.u >> 16) & 1u);
  return (uint16_t)(r >> 16);
}
__device__ __forceinline__ float elu1(float x) { return x > 0.f ? x : (expf(x) - 1.f); }

__device__ __forceinline__ void load8(const float* __restrict__ p, float* v) {
  const float4* q = (const float4*)p;
  float4 a = q[0], b = q[1];
  v[0]=a.x; v[1]=a.y; v[2]=a.z; v[3]=a.w; v[4]=b.x; v[5]=b.y; v[6]=b.z; v[7]=b.w;
}
__device__ __forceinline__ void load16(const float* __restrict__ p, float* v) {
  const float4* q = (const float4*)p;
  float4 a=q[0],b=q[1],c=q[2],d=q[3];
  v[0]=a.x; v[1]=a.y; v[2]=a.z; v[3]=a.w;
  v[4]=b.x; v[5]=b.y; v[6]=b.z; v[7]=b.w;
  v[8]=c.x; v[9]=c.y; v[10]=c.z; v[11]=c.w;
  v[12]=d.x; v[13]=d.y; v[14]=d.z; v[15]=d.w;
}
__device__ __forceinline__ void store16(float* __restrict__ p, const float* v) {
  float4* q = (float4*)p;
  q[0] = make_float4(v[0],v[1],v[2],v[3]);
  q[1] = make_float4(v[4],v[5],v[6],v[7]);
  q[2] = make_float4(v[8],v[9],v[10],v[11]);
  q[3] = make_float4(v[12],v[13],v[14],v[15]);
}

// ---------------- GAT part (fp32) ----------------

__global__ void proj12(const float* __restrict__ x,
                       const float* __restrict__ Ws1, const float* __restrict__ Wd1,
                       const float* __restrict__ Ws2, const float* __restrict__ Wd2,
                       float* __restrict__ fs1, float* __restrict__ fd1,
                       float* __restrict__ fs2, float* __restrict__ fd2) {
  __shared__ float w[4][128];
  int tid = threadIdx.x;
  if (tid < 128) {
    w[0][tid] = Ws1[tid]; w[1][tid] = Wd1[tid];
    w[2][tid] = Ws2[tid]; w[3][tid] = Wd2[tid];
  }
  __syncthreads();
  int n = blockIdx.x * 256 + tid;
  if (n >= NN) return;
  float xi[8]; load8(x + (size_t)n * 8, xi);
  float o[16];
  float* outs[4] = {fs1, fd1, fs2, fd2};
  #pragma unroll
  for (int m = 0; m < 4; ++m) {
    #pragma unroll
    for (int j = 0; j < 16; ++j) {
      float a = 0.f;
      #pragma unroll
      for (int i = 0; i < 8; ++i) a += xi[i] * w[m][i*16 + j];
      o[j] = a;
    }
    store16(outs[m] + (size_t)n * 16, o);
  }
}

__device__ __forceinline__ void edge_one(const float* __restrict__ fsr, const float* __restrict__ fdr,
                                         const float* __restrict__ attn,
                                         float* __restrict__ accr, float* __restrict__ zr) {
  float fs[16], fd[16], at[16];
  load16(fsr, fs); load16(fdr, fd); load16(attn, at);
  #pragma unroll
  for (int h = 0; h < 2; ++h) {
    float s = 0.f;
    #pragma unroll
    for (int d = 0; d < 8; ++d) {
      float e = fs[h*8+d] + fd[h*8+d];
      e = e > 0.f ? e : 0.2f * e;          // GATv2 leaky slope
      s += e * at[h*8+d];
    }
    float p = expf(s);                      // deferred-norm softmax (shift-free, |s| small)
    unsafeAtomicAdd(zr + h, p);
    #pragma unroll
    for (int d = 0; d < 8; ++d) unsafeAtomicAdd(accr + h*8 + d, p * fs[h*8+d]);
  }
}

__global__ void edge12(const int* __restrict__ src, const int* __restrict__ dst,
                       const float* __restrict__ fs1, const float* __restrict__ fd1,
                       const float* __restrict__ fs2, const float* __restrict__ fd2,
                       const float* __restrict__ at1, const float* __restrict__ at2,
                       float* acc1, float* z1, float* acc2, float* z2) {
  int e = blockIdx.x * 256 + threadIdx.x;
  if (e >= NE) return;
  int s = src[e], d = dst[e];
  edge_one(fs1 + (size_t)s*16, fd1 + (size_t)d*16, at1, acc1 + (size_t)d*16, z1 + (size_t)d*2);
  edge_one(fs2 + (size_t)s*16, fd2 + (size_t)d*16, at2, acc2 + (size_t)d*16, z2 + (size_t)d*2);
}

__global__ void edge3(const int* __restrict__ src, const int* __restrict__ dst,
                      const float* __restrict__ fs3, const float* __restrict__ fd3,
                      const float* __restrict__ at3, float* acc3, float* z3) {
  int e = blockIdx.x * 256 + threadIdx.x;
  if (e >= NE) return;
  int s = src[e], d = dst[e];
  edge_one(fs3 + (size_t)s*16, fd3 + (size_t)d*16, at3, acc3 + (size_t)d*16, z3 + (size_t)d*2);
}

__global__ void fin12(const float* __restrict__ x,
                      const float* __restrict__ acc1, const float* __restrict__ z1,
                      const float* __restrict__ re1, const float* __restrict__ bi1,
                      const float* __restrict__ acc2, const float* __restrict__ z2,
                      const float* __restrict__ re2, const float* __restrict__ bi2,
                      float* __restrict__ hin, float* __restrict__ hdef1) {
  __shared__ float r1[128], r2[128], b1s[16], b2s[16];
  int tid = threadIdx.x;
  if (tid < 128) { r1[tid] = re1[tid]; r2[tid] = re2[tid]; }
  if (tid < 16)  { b1s[tid] = bi1[tid]; b2s[tid] = bi2[tid]; }
  __syncthreads();
  int n = blockIdx.x * 256 + tid;
  if (n >= NN) return;
  float xi[8]; load8(x + (size_t)n * 8, xi);
  float a1[16], a2[16];
  load16(acc1 + (size_t)n*16, a1);
  load16(acc2 + (size_t)n*16, a2);
  float z10 = z1[(size_t)n*2], z11 = z1[(size_t)n*2+1];
  float z20 = z2[(size_t)n*2], z21 = z2[(size_t)n*2+1];
  #pragma unroll
  for (int j = 0; j < 16; ++j) {
    float r = 0.f;
    #pragma unroll
    for (int i = 0; i < 8; ++i) r += xi[i] * r1[i*16 + j];
    float zz = (j < 8) ? z10 : z11;
    float v = (zz > 0.f ? a1[j] / zz : 0.f) + r + b1s[j];
    hin[(size_t)n*40 + j] = elu1(v);                       // h_att1 -> cols 0..15
  }
  #pragma unroll
  for (int j = 0; j < 16; ++j) {
    float r = 0.f;
    #pragma unroll
    for (int i = 0; i < 8; ++i) r += xi[i] * r2[i*16 + j];
    float zz = (j < 8) ? z20 : z21;
    float v = (zz > 0.f ? a2[j] / zz : 0.f) + r + b2s[j];
    hdef1[(size_t)n*16 + j] = elu1(v);                     // h_def1 (layer-3 input)
  }
  #pragma unroll
  for (int i = 0; i < 8; ++i) hin[(size_t)n*40 + 32 + i] = xi[i];  // x -> cols 32..39
}

__global__ void proj3(const float* __restrict__ hd,
                      const float* __restrict__ Ws3, const float* __restrict__ Wd3,
                      float* __restrict__ fs3, float* __restrict__ fd3) {
  __shared__ float ws[256], wd[256];
  int tid = threadIdx.x;
  ws[tid] = Ws3[tid]; wd[tid] = Wd3[tid];
  __syncthreads();
  int n = blockIdx.x * 256 + tid;
  if (n >= NN) return;
  float h[16]; load16(hd + (size_t)n*16, h);
  float o[16];
  #pragma unroll
  for (int j = 0; j < 16; ++j) {
    float a = 0.f;
    #pragma unroll
    for (int i = 0; i < 16; ++i) a += h[i] * ws[i*16 + j];
    o[j] = a;
  }
  store16(fs3 + (size_t)n*16, o);
  #pragma unroll
  for (int j = 0; j < 16; ++j) {
    float a = 0.f;
    #pragma unroll
    for (int i = 0; i < 16; ++i) a += h[i] * wd[i*16 + j];
    o[j] = a;
  }
  store16(fd3 + (size_t)n*16, o);
}

__global__ void fin3(const float* __restrict__ hd,
                     const float* __restrict__ acc3, const float* __restrict__ z3,
                     const float* __restrict__ bi3, float* __restrict__ hin) {
  __shared__ float b3s[16];
  int tid = threadIdx.x;
  if (tid < 16) b3s[tid] = bi3[tid];
  __syncthreads();
  int n = blockIdx.x * 256 + tid;
  if (n >= NN) return;
  float a[16], h[16];
  load16(acc3 + (size_t)n*16, a);
  load16(hd + (size_t)n*16, h);
  float z0 = z3[(size_t)n*2], z1v = z3[(size_t)n*2+1];
  #pragma unroll
  for (int j = 0; j < 16; ++j) {
    float zz = (j < 8) ? z0 : z1v;
    float v = (zz > 0.f ? a[j] / zz : 0.f) + h[j] + b3s[j]; // identity residual
    hin[(size_t)n*40 + 16 + j] = elu1(v);                   // h_def2 -> cols 16..31
  }
}

// ---------------- MLP part (bf16 MFMA) ----------------

// transpose fp32 [R][C] -> bf16 outT[c][r] with leading dim ldout (pads pre-zeroed by memset)
__global__ void transpose_to_bf16(const float* __restrict__ in, uint16_t* __restrict__ outT,
                                  int R, int C, int ldout) {
  __shared__ float t[32][33];
  int rb = blockIdx.x * 32, cb = blockIdx.y * 32;
  int tx = threadIdx.x & 31, ty = threadIdx.x >> 5;
  #pragma unroll
  for (int y = ty; y < 32; y += 8) {
    int r = rb + y, c = cb + tx;
    t[y][tx] = (r < R && c < C) ? in[(size_t)r * C + c] : 0.f;
  }
  __syncthreads();
  #pragma unroll
  for (int y = ty; y < 32; y += 8) {
    int c = cb + y, r = rb + tx;
    if (c < C && r < R) outT[(size_t)c * ldout + r] = f2bf(t[tx][y]);
  }
}

// hin fp32 [NN][40] -> bf16 [60032][64] (K padded to 64 with zeros, rows padded with zeros)
__global__ void pack_hin(const float* __restrict__ hin, uint16_t* __restrict__ hinb) {
  int idx = blockIdx.x * 256 + threadIdx.x;   // grid exactly covers 60032*64
  int n = idx >> 6, j = idx & 63;
  float v = (n < NN && j < 40) ? hin[(size_t)n*40 + j] : 0.f;
  hinb[idx] = f2bf(v);
}

__device__ __forceinline__ void gload16(const void* g, void* l) {
  __builtin_amdgcn_global_load_lds((const __attribute__((address_space(1))) unsigned int*)g,
                                   (__attribute__((address_space(3))) unsigned int*)l, 16, 0, 0);
}

// C[m][n] = act( sum_k A[m][k]*Bt[n][k] + bias[n] ), act = leaky_relu(slope)
// A: [rows][K] bf16, Bt: [ntiles*128][K] bf16 (padded rows zero). 128x128 tile, BK=32,
// 4 waves in 2x2, 64x64 per wave (m97 structure).
template <bool OUT_BF16>
__global__ __launch_bounds__(256) void gemm_bt(const uint16_t* __restrict__ A,
                                               const uint16_t* __restrict__ Bt,
                                               const float* __restrict__ bias,
                                               void* __restrict__ Cout,
                                               int K, int ldC, int Nreal, float slope) {
  __shared__ __align__(16) uint16_t As[128 * 32];
  __shared__ __align__(16) uint16_t Bs[128 * 32];
  const int tid = threadIdx.x;
  const int lane = tid & 63;
  const int wave = tid >> 6;
  const int wm = (wave >> 1) * 64;
  const int wn = (wave & 1) * 64;
  const long nt = (long)blockIdx.x * 128;   // n fast: A-panel reused across 13 n-tiles
  const long mt = (long)blockIdx.y * 128;

  const int c0 = tid, c1 = tid + 256;       // 512 16B-chunks per 8KB tile
  const int r0 = c0 >> 2, k0o = (c0 & 3) * 8;
  const int r1 = c1 >> 2, k1o = (c1 & 3) * 8;
  const uint16_t* Ag0 = A + (mt + r0) * (long)K + k0o;
  const uint16_t* Ag1 = A + (mt + r1) * (long)K + k1o;
  const uint16_t* Bg0 = Bt + (nt + r0) * (long)K + k0o;
  const uint16_t* Bg1 = Bt + (nt + r1) * (long)K + k1o;
  uint16_t* As0 = As + c0 * 8; uint16_t* As1 = As + c1 * 8;
  uint16_t* Bs0 = Bs + c0 * 8; uint16_t* Bs1 = Bs + c1 * 8;
  const int fo = (lane & 15) * 32 + (lane >> 4) * 8;  // frag: row=lane&15, k-group=lane>>4

  f32x4 acc[4][4] = {};

  for (int kk = 0; kk < K; kk += 32) {
    gload16(Ag0 + kk, As0);
    gload16(Ag1 + kk, As1);
    gload16(Bg0 + kk, Bs0);
    gload16(Bg1 + kk, Bs1);
    __syncthreads();           // compiler drains vmcnt before barrier
    s16x8 a[4], b[4];
    #pragma unroll
    for (int i = 0; i < 4; ++i) a[i] = *(const s16x8*)(As + (wm + i*16)*32 + fo);
    #pragma unroll
    for (int j = 0; j < 4; ++j) b[j] = *(const s16x8*)(Bs + (wn + j*16)*32 + fo);
    #pragma unroll
    for (int i = 0; i < 4; ++i) {
      #pragma unroll
      for (int j = 0; j < 4; ++j)
        acc[i][j] = __builtin_amdgcn_mfma_f32_16x16x32_bf16(a[i], b[j], acc[i][j], 0, 0, 0);
    }
    __syncthreads();
  }

  // C/D layout (verified m89/m91): col = lane&15, row = (lane>>4)*4 + t
  const int cr = (lane >> 4) * 4;
  const int cc = lane & 15;
  #pragma unroll
  for (int j = 0; j < 4; ++j) {
    const long col = nt + wn + j*16 + cc;
    if (col >= Nreal) continue;
    const float bv = bias[col];
    #pragma unroll
    for (int i = 0; i < 4; ++i) {
      #pragma unroll
      for (int t = 0; t < 4; ++t) {
        const long row = mt + wm + i*16 + cr + t;
        float v = acc[i][j][t] + bv;
        v = v > 0.f ? v : slope * v;
        if (OUT_BF16) ((uint16_t*)Cout)[row * (long)ldC + col] = f2bf(v);
        else          ((float*)Cout)[row * (long)ldC + col] = v;
      }
    }
  }
}

__global__ void mlp4(const float* __restrict__ h3, const float* __restrict__ W4,
                     const float* __restrict__ b4, float* __restrict__ out,
                     int m0, int rows) {
  int r = blockIdx.x * 256 + threadIdx.x;
  if (r >= rows) return;
  const float* t = h3 + (size_t)r * 40;
  float a = 0.f;
  #pragma unroll
  for (int k = 0; k < 40; k += 4) {
    float4 tv = *(const float4*)(t + k);
    float4 wv = *(const float4*)(W4 + k);
    a += tv.x*wv.x + tv.y*wv.y + tv.z*wv.z + tv.w*wv.w;
  }
  a += b4[0];
  out[m0 + r] = 1.f / (1.f + expf(-a));
}

// ---------------- host ----------------

extern "C" void kernel_launch(void* const* d_in, const int* in_sizes, int n_in,
                              void* d_out, int out_size, void* d_ws, size_t ws_size,
                              hipStream_t stream) {
  const float* x   = (const float*)d_in[0];
  const int*   src = (const int*)d_in[1];
  const int*   dst = (const int*)d_in[2];
  const float* Ws1 = (const float*)d_in[3];
  const float* Wd1 = (const float*)d_in[4];
  const float* at1 = (const float*)d_in[5];
  const float* bi1 = (const float*)d_in[6];
  const float* re1 = (const float*)d_in[7];
  const float* Ws2 = (const float*)d_in[8];
  const float* Wd2 = (const float*)d_in[9];
  const float* at2 = (const float*)d_in[10];
  const float* bi2 = (const float*)d_in[11];
  const float* re2 = (const float*)d_in[12];
  const float* Ws3 = (const float*)d_in[13];
  const float* Wd3 = (const float*)d_in[14];
  const float* at3 = (const float*)d_in[15];
  const float* bi3 = (const float*)d_in[16];
  const float* W1  = (const float*)d_in[17];
  const float* b1  = (const float*)d_in[18];
  const float* W2  = (const float*)d_in[19];
  const float* b2  = (const float*)d_in[20];
  const float* W3  = (const float*)d_in[21];
  const float* b3  = (const float*)d_in[22];
  const float* W4  = (const float*)d_in[23];
  const float* b4  = (const float*)d_in[24];
  float* out = (float*)d_out;

  char* ws = (char*)d_ws;
  size_t off = 0;
  auto alloc = [&](size_t bytes) -> void* {
    off = (off + 255) & ~(size_t)255;
    void* p = ws + off;
    off += bytes;
    return p;
  };
  const size_t NF16 = (size_t)NN * 16 * 4;
  const size_t NZ   = (size_t)NN * 2 * 4;
  float* fs1 = (float*)alloc(NF16);
  float* fd1 = (float*)alloc(NF16);
  float* fs2 = (float*)alloc(NF16);
  float* fd2 = (float*)alloc(NF16);
  float* fs3 = (float*)alloc(NF16);
  float* fd3 = (float*)alloc(NF16);
  float* acc1 = (float*)alloc(NF16);   // acc1..z3 contiguous: zeroed with one memset
  float* z1   = (float*)alloc(NZ);
  float* acc2 = (float*)alloc(NF16);
  float* z2   = (float*)alloc(NZ);
  float* acc3 = (float*)alloc(NF16);
  float* z3   = (float*)alloc(NZ);
  float* hdef1 = (float*)alloc(NF16);
  float* hin   = (float*)alloc((size_t)NN * 40 * 4);
  uint16_t* hinb = (uint16_t*)alloc((size_t)60032 * 64 * 2);
  uint16_t* W1T  = (uint16_t*)alloc((size_t)1664 * 64 * 2);
  uint16_t* W2T  = (uint16_t*)alloc((size_t)1664 * 1600 * 2);
  uint16_t* W3T  = (uint16_t*)alloc((size_t)128 * 1600 * 2);

  // adaptive node-chunking for the MLP so h1/h2/h3 fit in ws
  size_t fixed_end = (off + 255) & ~(size_t)255;
  size_t avail = (ws_size > fixed_end + 4096) ? (ws_size - fixed_end - 4096) : 0;
  long mc = (long)(avail / 6560);      // per-row bytes: 2*1600*2 + 40*4
  mc = (mc / 128) * 128;
  if (mc > 60032) mc = 60032;
  if (mc < 128) mc = 128;
  uint16_t* h1c = (uint16_t*)alloc((size_t)mc * 1600 * 2);
  uint16_t* h2c = (uint16_t*)alloc((size_t)mc * 1600 * 2);
  float*    h3c = (float*)alloc((size_t)mc * 40 * 4);

  size_t zlen = (size_t)((char*)hdef1 - (char*)acc1);
  hipMemsetAsync(acc1, 0, zlen, stream);
  hipMemsetAsync(W1T, 0, (size_t)1664 * 64 * 2, stream);
  hipMemsetAsync(W3T, 0, (size_t)128 * 1600 * 2, stream);
  hipMemsetAsync(W2T + (size_t)1600 * 1600, 0, (size_t)64 * 1600 * 2, stream);

  transpose_to_bf16<<<dim3(2, 50), 256, 0, stream>>>(W1, W1T, 40, 1600, 64);
  transpose_to_bf16<<<dim3(50, 50), 256, 0, stream>>>(W2, W2T, 1600, 1600, 1600);
  transpose_to_bf16<<<dim3(50, 2), 256, 0, stream>>>(W3, W3T, 1600, 40, 1600);

  const int NB = (NN + 255) / 256;
  const int EB = (NE + 255) / 256;
  proj12<<<NB, 256, 0, stream>>>(x, Ws1, Wd1, Ws2, Wd2, fs1, fd1, fs2, fd2);
  edge12<<<EB, 256, 0, stream>>>(src, dst, fs1, fd1, fs2, fd2, at1, at2, acc1, z1, acc2, z2);
  fin12<<<NB, 256, 0, stream>>>(x, acc1, z1, re1, bi1, acc2, z2, re2, bi2, hin, hdef1);
  proj3<<<NB, 256, 0, stream>>>(hdef1, Ws3, Wd3, fs3, fd3);
  edge3<<<EB, 256, 0, stream>>>(src, dst, fs3, fd3, at3, acc3, z3);
  fin3<<<NB, 256, 0, stream>>>(hdef1, acc3, z3, bi3, hin);
  pack_hin<<<15008, 256, 0, stream>>>(hin, hinb);

  for (long m0 = 0; m0 < NN; m0 += mc) {
    long rows_real = NN - m0; if (rows_real > mc) rows_real = mc;
    long rows_pad = (rows_real + 127) & ~127L;
    dim3 g1(13, (unsigned)(rows_pad / 128));
    gemm_bt<true><<<g1, 256, 0, stream>>>(hinb + m0 * 64, W1T, b1, h1c, 64, 1600, 1600, 0.01f);
    gemm_bt<true><<<g1, 256, 0, stream>>>(h1c, W2T, b2, h2c, 1600, 1600, 1600, 0.01f);
    dim3 g3(1, (unsigned)(rows_pad / 128));
    gemm_bt<false><<<g3, 256, 0, stream>>>(h2c, W3T, b3, h3c, 1600, 40, 40, 0.01f);
    mlp4<<<(unsigned)((rows_real + 255) / 256), 256, 0, stream>>>(h3c, W4, b4, out, (int)m0, (int)rows_real);
  }
}

// Round 2
// 1063.925 us; speedup vs baseline: 5.7023x; 5.7023x over previous
//
#include <hip/hip_runtime.h>
#include <stdint.h>

#define NN 60000
#define NE 1920000
#define NB_NODE 235   // ceil(60000/256)

typedef float f32x4 __attribute__((ext_vector_type(4)));
typedef short s16x8 __attribute__((ext_vector_type(8)));

__device__ __forceinline__ uint16_t f2bf(float f) {
  union { float f; uint32_t u; } v; v.f = f;
  uint32_t r = v.u + 0x7FFFu + ((v.u >> 16) & 1u);
  return (uint16_t)(r >> 16);
}
__device__ __forceinline__ uint32_t pack2(float a, float b) {
  return (uint32_t)f2bf(a) | ((uint32_t)f2bf(b) << 16);
}
__device__ __forceinline__ float elu1(float x) { return x > 0.f ? x : (__expf(x) - 1.f); }

__device__ __forceinline__ void load8(const float* __restrict__ p, float* v) {
  const float4* q = (const float4*)p;
  float4 a = q[0], b = q[1];
  v[0]=a.x; v[1]=a.y; v[2]=a.z; v[3]=a.w; v[4]=b.x; v[5]=b.y; v[6]=b.z; v[7]=b.w;
}
__device__ __forceinline__ void load16(const float* __restrict__ p, float* v) {
  load8(p, v); load8(p + 8, v + 8);
}
__device__ __forceinline__ void store16(float* __restrict__ p, const float* v) {
  float4* q = (float4*)p;
  q[0] = make_float4(v[0],v[1],v[2],v[3]);
  q[1] = make_float4(v[4],v[5],v[6],v[7]);
  q[2] = make_float4(v[8],v[9],v[10],v[11]);
  q[3] = make_float4(v[12],v[13],v[14],v[15]);
}

// ---------------- CSR build ----------------

__global__ void hist_k(const int* __restrict__ dst, int* __restrict__ deg) {
  int e = blockIdx.x * 256 + threadIdx.x;
  if (e >= NE) return;
  atomicAdd(&deg[dst[e]], 1);
}

__global__ void scan_block(const int* __restrict__ deg, int* __restrict__ bsum) {
  __shared__ int t[256];
  int i = blockIdx.x * 256 + threadIdx.x;
  t[threadIdx.x] = (i < NN) ? deg[i] : 0;
  __syncthreads();
  for (int s = 128; s > 0; s >>= 1) {
    if (threadIdx.x < s) t[threadIdx.x] += t[threadIdx.x + s];
    __syncthreads();
  }
  if (threadIdx.x == 0) bsum[blockIdx.x] = t[0];
}

__global__ void scan_tops(int* __restrict__ bsum) {   // 1 block, 256 >= NB_NODE
  __shared__ int t[256];
  int v = (threadIdx.x < NB_NODE) ? bsum[threadIdx.x] : 0;
  t[threadIdx.x] = v;
  __syncthreads();
  for (int s = 1; s < 256; s <<= 1) {
    int u = (threadIdx.x >= s) ? t[threadIdx.x - s] : 0;
    __syncthreads();
    t[threadIdx.x] += u;
    __syncthreads();
  }
  if (threadIdx.x < NB_NODE) bsum[threadIdx.x] = t[threadIdx.x] - v;  // exclusive
}

__global__ void scan_write(const int* __restrict__ deg, const int* __restrict__ bsum,
                           int* __restrict__ rowp, int* __restrict__ cur) {
  __shared__ int t[256];
  int i = blockIdx.x * 256 + threadIdx.x;
  int v = (i < NN) ? deg[i] : 0;
  t[threadIdx.x] = v;
  __syncthreads();
  for (int s = 1; s < 256; s <<= 1) {
    int u = (threadIdx.x >= s) ? t[threadIdx.x - s] : 0;
    __syncthreads();
    t[threadIdx.x] += u;
    __syncthreads();
  }
  if (i < NN) {
    int ex = bsum[blockIdx.x] + t[threadIdx.x] - v;
    rowp[i] = ex;
    cur[i] = ex;
  }
}

__global__ void scatter_k(const int* __restrict__ src, const int* __restrict__ dst,
                          int* __restrict__ cur, int* __restrict__ ssrc) {
  int e = blockIdx.x * 256 + threadIdx.x;
  if (e >= NE) return;
  int d = dst[e];
  int pos = atomicAdd(&cur[d], 1);
  ssrc[pos] = src[e];
}

// ---------------- GAT projections ----------------

// fs12[n][32] = [fs1(16) | fs2(16)], fd12[n][32] = [fd1(16) | fd2(16)]
__global__ void proj12(const float* __restrict__ x,
                       const float* __restrict__ Ws1, const float* __restrict__ Wd1,
                       const float* __restrict__ Ws2, const float* __restrict__ Wd2,
                       float* __restrict__ fs12, float* __restrict__ fd12) {
  __shared__ float w[4][128];
  int tid = threadIdx.x;
  if (tid < 128) {
    w[0][tid] = Ws1[tid]; w[1][tid] = Wd1[tid];
    w[2][tid] = Ws2[tid]; w[3][tid] = Wd2[tid];
  }
  __syncthreads();
  int n = blockIdx.x * 256 + tid;
  if (n >= NN) return;
  float xi[8]; load8(x + (size_t)n * 8, xi);
  float o[16];
  #pragma unroll
  for (int m = 0; m < 4; ++m) {
    #pragma unroll
    for (int j = 0; j < 16; ++j) {
      float a = 0.f;
      #pragma unroll
      for (int i = 0; i < 8; ++i) a += xi[i] * w[m][i*16 + j];
      o[j] = a;
    }
    float* base = (m & 1) ? fd12 : fs12;
    store16(base + (size_t)n * 32 + (m >> 1) * 16, o);
  }
}

__global__ void proj3(const float* __restrict__ hd,
                      const float* __restrict__ Ws3, const float* __restrict__ Wd3,
                      float* __restrict__ fs3, float* __restrict__ fd3) {
  __shared__ float ws[256], wd[256];
  int tid = threadIdx.x;
  ws[tid] = Ws3[tid]; wd[tid] = Wd3[tid];
  __syncthreads();
  int n = blockIdx.x * 256 + tid;
  if (n >= NN) return;
  float h[16]; load16(hd + (size_t)n*16, h);
  float o[16];
  #pragma unroll
  for (int j = 0; j < 16; ++j) {
    float a = 0.f;
    #pragma unroll
    for (int i = 0; i < 16; ++i) a += h[i] * ws[i*16 + j];
    o[j] = a;
  }
  store16(fs3 + (size_t)n*16, o);
  #pragma unroll
  for (int j = 0; j < 16; ++j) {
    float a = 0.f;
    #pragma unroll
    for (int i = 0; i < 16; ++i) a += h[i] * wd[i*16 + j];
    o[j] = a;
  }
  store16(fd3 + (size_t)n*16, o);
}

// ---------------- gathers (no atomics; per-node register accumulation) ----------------

// layers 1+2 fused: writes hinb cols 0..15 (h_att1 bf16), cols 32..39 (x), zeros 40..63,
// and hdef1 fp32 (layer-3 input).
__global__ __launch_bounds__(256) void gather12(
    const int* __restrict__ rowp, const int* __restrict__ deg, const int* __restrict__ ssrc,
    const float* __restrict__ fs12, const float* __restrict__ fd12,
    const float* __restrict__ at1, const float* __restrict__ at2,
    const float* __restrict__ x,
    const float* __restrict__ re1, const float* __restrict__ bi1,
    const float* __restrict__ re2, const float* __restrict__ bi2,
    uint32_t* __restrict__ hinb32, float* __restrict__ hdef1) {
  __shared__ float r1[128], r2[128], b1s[16], b2s[16];
  int tid = threadIdx.x;
  if (tid < 128) { r1[tid] = re1[tid]; r2[tid] = re2[tid]; }
  if (tid < 16)  { b1s[tid] = bi1[tid]; b2s[tid] = bi2[tid]; }
  __syncthreads();
  int n = blockIdx.x * 256 + tid;
  if (n >= NN) return;

  float at[32];
  #pragma unroll
  for (int i = 0; i < 16; ++i) at[i] = at1[i];
  #pragma unroll
  for (int i = 0; i < 16; ++i) at[16 + i] = at2[i];

  float fd[32];
  load16(fd12 + (size_t)n * 32, fd);
  load16(fd12 + (size_t)n * 32 + 16, fd + 16);

  float acc[32];
  #pragma unroll
  for (int i = 0; i < 32; ++i) acc[i] = 0.f;
  float z[4] = {0.f, 0.f, 0.f, 0.f};

  int s0 = rowp[n], d = deg[n];
  for (int i = 0; i < d; ++i) {
    int s = ssrc[s0 + i];
    const float* fp = fs12 + (size_t)s * 32;
    float fs[32];
    load16(fp, fs);
    load16(fp + 16, fs + 16);
    #pragma unroll
    for (int L = 0; L < 2; ++L) {
      #pragma unroll
      for (int h = 0; h < 2; ++h) {
        float sc = 0.f;
        #pragma unroll
        for (int d0 = 0; d0 < 8; ++d0) {
          int ix = L*16 + h*8 + d0;
          float e = fs[ix] + fd[ix];
          e = e > 0.f ? e : 0.2f * e;      // GATv2 leaky slope
          sc += e * at[ix];
        }
        float p = __expf(sc);              // deferred-norm softmax
        z[L*2 + h] += p;
        #pragma unroll
        for (int d0 = 0; d0 < 8; ++d0) {
          int ix = L*16 + h*8 + d0;
          acc[ix] += p * fs[ix];
        }
      }
    }
  }

  float xi[8]; load8(x + (size_t)n * 8, xi);
  uint32_t* row = hinb32 + (size_t)n * 32;   // 64 bf16 cols = 32 u32 words

  // layer 1 -> hinb cols 0..15
  float v1[16];
  #pragma unroll
  for (int j = 0; j < 16; ++j) {
    float r = 0.f;
    #pragma unroll
    for (int i = 0; i < 8; ++i) r += xi[i] * r1[i*16 + j];
    float zz = z[j >> 3];
    float v = (zz > 0.f ? acc[j] / zz : 0.f) + r + b1s[j];
    v1[j] = elu1(v);
  }
  #pragma unroll
  for (int w = 0; w < 8; ++w) row[w] = pack2(v1[2*w], v1[2*w+1]);

  // layer 2 -> hdef1 fp32
  float v2[16];
  #pragma unroll
  for (int j = 0; j < 16; ++j) {
    float r = 0.f;
    #pragma unroll
    for (int i = 0; i < 8; ++i) r += xi[i] * r2[i*16 + j];
    float zz = z[2 + (j >> 3)];
    float v = (zz > 0.f ? acc[16 + j] / zz : 0.f) + r + b2s[j];
    v2[j] = elu1(v);
  }
  store16(hdef1 + (size_t)n * 16, v2);

  // x -> cols 32..39, zeros -> cols 40..63
  #pragma unroll
  for (int w = 0; w < 4; ++w) row[16 + w] = pack2(xi[2*w], xi[2*w+1]);
  #pragma unroll
  for (int w = 20; w < 32; ++w) row[w] = 0u;
}

// layer 3: identity residual; writes hinb cols 16..31
__global__ __launch_bounds__(256) void gather3(
    const int* __restrict__ rowp, const int* __restrict__ deg, const int* __restrict__ ssrc,
    const float* __restrict__ fs3, const float* __restrict__ fd3,
    const float* __restrict__ at3, const float* __restrict__ bi3,
    const float* __restrict__ hdef1, uint32_t* __restrict__ hinb32) {
  __shared__ float b3s[16];
  int tid = threadIdx.x;
  if (tid < 16) b3s[tid] = bi3[tid];
  __syncthreads();
  int n = blockIdx.x * 256 + tid;
  if (n >= NN) return;

  float at[16];
  #pragma unroll
  for (int i = 0; i < 16; ++i) at[i] = at3[i];
  float fd[16];
  load16(fd3 + (size_t)n * 16, fd);

  float acc[16];
  #pragma unroll
  for (int i = 0; i < 16; ++i) acc[i] = 0.f;
  float z[2] = {0.f, 0.f};

  int s0 = rowp[n], d = deg[n];
  for (int i = 0; i < d; ++i) {
    int s = ssrc[s0 + i];
    float fs[16];
    load16(fs3 + (size_t)s * 16, fs);
    #pragma unroll
    for (int h = 0; h < 2; ++h) {
      float sc = 0.f;
      #pragma unroll
      for (int d0 = 0; d0 < 8; ++d0) {
        int ix = h*8 + d0;
        float e = fs[ix] + fd[ix];
        e = e > 0.f ? e : 0.2f * e;
        sc += e * at[ix];
      }
      float p = __expf(sc);
      z[h] += p;
      #pragma unroll
      for (int d0 = 0; d0 < 8; ++d0) {
        int ix = h*8 + d0;
        acc[ix] += p * fs[ix];
      }
    }
  }

  float hd[16];
  load16(hdef1 + (size_t)n * 16, hd);
  uint32_t* row = hinb32 + (size_t)n * 32;
  float v[16];
  #pragma unroll
  for (int j = 0; j < 16; ++j) {
    float zz = z[j >> 3];
    float o = (zz > 0.f ? acc[j] / zz : 0.f) + hd[j] + b3s[j];
    v[j] = elu1(o);
  }
  #pragma unroll
  for (int w = 0; w < 8; ++w) row[8 + w] = pack2(v[2*w], v[2*w+1]);
}

// ---------------- MLP part (bf16 MFMA) ----------------

__global__ void transpose_to_bf16(const float* __restrict__ in, uint16_t* __restrict__ outT,
                                  int R, int C, int ldout) {
  __shared__ float t[32][33];
  int rb = blockIdx.x * 32, cb = blockIdx.y * 32;
  int tx = threadIdx.x & 31, ty = threadIdx.x >> 5;
  #pragma unroll
  for (int y = ty; y < 32; y += 8) {
    int r = rb + y, c = cb + tx;
    t[y][tx] = (r < R && c < C) ? in[(size_t)r * C + c] : 0.f;
  }
  __syncthreads();
  #pragma unroll
  for (int y = ty; y < 32; y += 8) {
    int c = cb + y, r = rb + tx;
    if (c < C && r < R) outT[(size_t)c * ldout + r] = f2bf(t[tx][y]);
  }
}

__device__ __forceinline__ void gload16(const void* g, void* l) {
  __builtin_amdgcn_global_load_lds((const __attribute__((address_space(1))) unsigned int*)g,
                                   (__attribute__((address_space(3))) unsigned int*)l, 16, 0, 0);
}

template <bool OUT_BF16>
__global__ __launch_bounds__(256) void gemm_bt(const uint16_t* __restrict__ A,
                                               const uint16_t* __restrict__ Bt,
                                               const float* __restrict__ bias,
                                               void* __restrict__ Cout,
                                               int K, int ldC, int Nreal, float slope) {
  __shared__ __align__(16) uint16_t As[128 * 32];
  __shared__ __align__(16) uint16_t Bs[128 * 32];
  const int tid = threadIdx.x;
  const int lane = tid & 63;
  const int wave = tid >> 6;
  const int wm = (wave >> 1) * 64;
  const int wn = (wave & 1) * 64;
  const long nt = (long)blockIdx.x * 128;
  const long mt = (long)blockIdx.y * 128;

  const int c0 = tid, c1 = tid + 256;
  const int r0 = c0 >> 2, k0o = (c0 & 3) * 8;
  const int r1 = c1 >> 2, k1o = (c1 & 3) * 8;
  const uint16_t* Ag0 = A + (mt + r0) * (long)K + k0o;
  const uint16_t* Ag1 = A + (mt + r1) * (long)K + k1o;
  const uint16_t* Bg0 = Bt + (nt + r0) * (long)K + k0o;
  const uint16_t* Bg1 = Bt + (nt + r1) * (long)K + k1o;
  uint16_t* As0 = As + c0 * 8; uint16_t* As1 = As + c1 * 8;
  uint16_t* Bs0 = Bs + c0 * 8; uint16_t* Bs1 = Bs + c1 * 8;
  const int fo = (lane & 15) * 32 + (lane >> 4) * 8;

  f32x4 acc[4][4] = {};

  for (int kk = 0; kk < K; kk += 32) {
    gload16(Ag0 + kk, As0);
    gload16(Ag1 + kk, As1);
    gload16(Bg0 + kk, Bs0);
    gload16(Bg1 + kk, Bs1);
    __syncthreads();
    s16x8 a[4], b[4];
    #pragma unroll
    for (int i = 0; i < 4; ++i) a[i] = *(const s16x8*)(As + (wm + i*16)*32 + fo);
    #pragma unroll
    for (int j = 0; j < 4; ++j) b[j] = *(const s16x8*)(Bs + (wn + j*16)*32 + fo);
    #pragma unroll
    for (int i = 0; i < 4; ++i) {
      #pragma unroll
      for (int j = 0; j < 4; ++j)
        acc[i][j] = __builtin_amdgcn_mfma_f32_16x16x32_bf16(a[i], b[j], acc[i][j], 0, 0, 0);
    }
    __syncthreads();
  }

  const int cr = (lane >> 4) * 4;
  const int cc = lane & 15;
  #pragma unroll
  for (int j = 0; j < 4; ++j) {
    const long col = nt + wn + j*16 + cc;
    if (col >= Nreal) continue;
    const float bv = bias[col];
    #pragma unroll
    for (int i = 0; i < 4; ++i) {
      #pragma unroll
      for (int t = 0; t < 4; ++t) {
        const long row = mt + wm + i*16 + cr + t;
        float v = acc[i][j][t] + bv;
        v = v > 0.f ? v : slope * v;
        if (OUT_BF16) ((uint16_t*)Cout)[row * (long)ldC + col] = f2bf(v);
        else          ((float*)Cout)[row * (long)ldC + col] = v;
      }
    }
  }
}

__global__ void mlp4(const float* __restrict__ h3, const float* __restrict__ W4,
                     const float* __restrict__ b4, float* __restrict__ out,
                     int m0, int rows) {
  int r = blockIdx.x * 256 + threadIdx.x;
  if (r >= rows) return;
  const float* t = h3 + (size_t)r * 40;
  float a = 0.f;
  #pragma unroll
  for (int k = 0; k < 40; k += 4) {
    float4 tv = *(const float4*)(t + k);
    float4 wv = *(const float4*)(W4 + k);
    a += tv.x*wv.x + tv.y*wv.y + tv.z*wv.z + tv.w*wv.w;
  }
  a += b4[0];
  out[m0 + r] = 1.f / (1.f + __expf(-a));
}

// ---------------- host ----------------

extern "C" void kernel_launch(void* const* d_in, const int* in_sizes, int n_in,
                              void* d_out, int out_size, void* d_ws, size_t ws_size,
                              hipStream_t stream) {
  const float* x   = (const float*)d_in[0];
  const int*   src = (const int*)d_in[1];
  const int*   dst = (const int*)d_in[2];
  const float* Ws1 = (const float*)d_in[3];
  const float* Wd1 = (const float*)d_in[4];
  const float* at1 = (const float*)d_in[5];
  const float* bi1 = (const float*)d_in[6];
  const float* re1 = (const float*)d_in[7];
  const float* Ws2 = (const float*)d_in[8];
  const float* Wd2 = (const float*)d_in[9];
  const float* at2 = (const float*)d_in[10];
  const float* bi2 = (const float*)d_in[11];
  const float* re2 = (const float*)d_in[12];
  const float* Ws3 = (const float*)d_in[13];
  const float* Wd3 = (const float*)d_in[14];
  const float* at3 = (const float*)d_in[15];
  const float* bi3 = (const float*)d_in[16];
  const float* W1  = (const float*)d_in[17];
  const float* b1  = (const float*)d_in[18];
  const float* W2  = (const float*)d_in[19];
  const float* b2  = (const float*)d_in[20];
  const float* W3  = (const float*)d_in[21];
  const float* b3  = (const float*)d_in[22];
  const float* W4  = (const float*)d_in[23];
  const float* b4  = (const float*)d_in[24];
  float* out = (float*)d_out;

  char* ws = (char*)d_ws;
  size_t off = 0;
  auto alloc = [&](size_t bytes) -> void* {
    off = (off + 255) & ~(size_t)255;
    void* p = ws + off;
    off += bytes;
    return p;
  };
  // CSR
  int* deg  = (int*)alloc((size_t)NN * 4);
  int* rowp = (int*)alloc((size_t)NN * 4);
  int* cur  = (int*)alloc((size_t)NN * 4);
  int* bsum = (int*)alloc((size_t)NB_NODE * 4);
  int* ssrc = (int*)alloc((size_t)NE * 4);
  // GAT features
  float* fs12  = (float*)alloc((size_t)NN * 32 * 4);
  float* fd12  = (float*)alloc((size_t)NN * 32 * 4);
  float* fs3   = (float*)alloc((size_t)NN * 16 * 4);
  float* fd3   = (float*)alloc((size_t)NN * 16 * 4);
  float* hdef1 = (float*)alloc((size_t)NN * 16 * 4);
  // MLP
  uint16_t* hinb = (uint16_t*)alloc((size_t)60032 * 64 * 2);
  uint16_t* W1T  = (uint16_t*)alloc((size_t)1664 * 64 * 2);
  uint16_t* W2T  = (uint16_t*)alloc((size_t)1664 * 1600 * 2);
  uint16_t* W3T  = (uint16_t*)alloc((size_t)128 * 1600 * 2);

  size_t fixed_end = (off + 255) & ~(size_t)255;
  size_t avail = (ws_size > fixed_end + 4096) ? (ws_size - fixed_end - 4096) : 0;
  long mc = (long)(avail / 6560);
  mc = (mc / 128) * 128;
  if (mc > 60032) mc = 60032;
  if (mc < 128) mc = 128;
  uint16_t* h1c = (uint16_t*)alloc((size_t)mc * 1600 * 2);
  uint16_t* h2c = (uint16_t*)alloc((size_t)mc * 1600 * 2);
  float*    h3c = (float*)alloc((size_t)mc * 40 * 4);

  hipMemsetAsync(deg, 0, (size_t)NN * 4, stream);
  hipMemsetAsync(hinb + (size_t)60000 * 64, 0, (size_t)32 * 64 * 2, stream);  // pad rows
  hipMemsetAsync(W1T, 0, (size_t)1664 * 64 * 2, stream);
  hipMemsetAsync(W3T, 0, (size_t)128 * 1600 * 2, stream);
  hipMemsetAsync(W2T + (size_t)1600 * 1600, 0, (size_t)64 * 1600 * 2, stream);

  const int EB = (NE + 255) / 256;
  // CSR build
  hist_k<<<EB, 256, 0, stream>>>(dst, deg);
  scan_block<<<NB_NODE, 256, 0, stream>>>(deg, bsum);
  scan_tops<<<1, 256, 0, stream>>>(bsum);
  scan_write<<<NB_NODE, 256, 0, stream>>>(deg, bsum, rowp, cur);
  scatter_k<<<EB, 256, 0, stream>>>(src, dst, cur, ssrc);

  // weight prep (independent; overlaps CSR on same stream serially, cheap)
  transpose_to_bf16<<<dim3(2, 50), 256, 0, stream>>>(W1, W1T, 40, 1600, 64);
  transpose_to_bf16<<<dim3(50, 50), 256, 0, stream>>>(W2, W2T, 1600, 1600, 1600);
  transpose_to_bf16<<<dim3(50, 2), 256, 0, stream>>>(W3, W3T, 1600, 40, 1600);

  // GAT
  proj12<<<NB_NODE, 256, 0, stream>>>(x, Ws1, Wd1, Ws2, Wd2, fs12, fd12);
  gather12<<<NB_NODE, 256, 0, stream>>>(rowp, deg, ssrc, fs12, fd12, at1, at2,
                                        x, re1, bi1, re2, bi2,
                                        (uint32_t*)hinb, hdef1);
  proj3<<<NB_NODE, 256, 0, stream>>>(hdef1, Ws3, Wd3, fs3, fd3);
  gather3<<<NB_NODE, 256, 0, stream>>>(rowp, deg, ssrc, fs3, fd3, at3, bi3,
                                       hdef1, (uint32_t*)hinb);

  // MLP
  for (long m0 = 0; m0 < NN; m0 += mc) {
    long rows_real = NN - m0; if (rows_real > mc) rows_real = mc;
    long rows_pad = (rows_real + 127) & ~127L;
    dim3 g1(13, (unsigned)(rows_pad / 128));
    gemm_bt<true><<<g1, 256, 0, stream>>>(hinb + m0 * 64, W1T, b1, h1c, 64, 1600, 1600, 0.01f);
    gemm_bt<true><<<g1, 256, 0, stream>>>(h1c, W2T, b2, h2c, 1600, 1600, 1600, 0.01f);
    dim3 g3(1, (unsigned)(rows_pad / 128));
    gemm_bt<false><<<g3, 256, 0, stream>>>(h2c, W3T, b3, h3c, 1600, 40, 40, 0.01f);
    mlp4<<<(unsigned)((rows_real + 255) / 256), 256, 0, stream>>>(h3c, W4, b4, out, (int)m0, (int)rows_real);
  }
}

// Round 3
// 956.149 us; speedup vs baseline: 6.3451x; 1.1127x over previous
//
#include <hip/hip_runtime.h>
#include <stdint.h>

#define NN 60000
#define NE 1920000
#define NB_NODE 235   // ceil(60000/256) for scan kernels
#define NB_PAIR 469   // ceil(60000/128) for 2-thread-per-node kernels

typedef float f32x4 __attribute__((ext_vector_type(4)));
typedef short s16x8 __attribute__((ext_vector_type(8)));

__device__ __forceinline__ uint16_t f2bf(float f) {
  union { float f; uint32_t u; } v; v.f = f;
  uint32_t r = v.u + 0x7FFFu + ((v.u >> 16) & 1u);
  return (uint16_t)(r >> 16);
}
__device__ __forceinline__ uint32_t pack2(float a, float b) {
  return (uint32_t)f2bf(a) | ((uint32_t)f2bf(b) << 16);
}
__device__ __forceinline__ float elu1(float x) { return x > 0.f ? x : (__expf(x) - 1.f); }

__device__ __forceinline__ void load8(const float* __restrict__ p, float* v) {
  const float4* q = (const float4*)p;
  float4 a = q[0], b = q[1];
  v[0]=a.x; v[1]=a.y; v[2]=a.z; v[3]=a.w; v[4]=b.x; v[5]=b.y; v[6]=b.z; v[7]=b.w;
}
__device__ __forceinline__ void load16(const float* __restrict__ p, float* v) {
  load8(p, v); load8(p + 8, v + 8);
}
__device__ __forceinline__ void store8(float* __restrict__ p, const float* v) {
  float4* q = (float4*)p;
  q[0] = make_float4(v[0],v[1],v[2],v[3]);
  q[1] = make_float4(v[4],v[5],v[6],v[7]);
}
__device__ __forceinline__ void store16(float* __restrict__ p, const float* v) {
  store8(p, v); store8(p + 8, v + 8);
}

// ---------------- CSR build ----------------

__global__ void hist_k(const int* __restrict__ dst, int* __restrict__ deg) {
  int e = blockIdx.x * 256 + threadIdx.x;
  if (e >= NE) return;
  atomicAdd(&deg[dst[e]], 1);
}

__global__ void scan_block(const int* __restrict__ deg, int* __restrict__ bsum) {
  __shared__ int t[256];
  int i = blockIdx.x * 256 + threadIdx.x;
  t[threadIdx.x] = (i < NN) ? deg[i] : 0;
  __syncthreads();
  for (int s = 128; s > 0; s >>= 1) {
    if (threadIdx.x < s) t[threadIdx.x] += t[threadIdx.x + s];
    __syncthreads();
  }
  if (threadIdx.x == 0) bsum[blockIdx.x] = t[0];
}

__global__ void scan_tops(int* __restrict__ bsum) {   // 1 block, 256 >= NB_NODE
  __shared__ int t[256];
  int v = (threadIdx.x < NB_NODE) ? bsum[threadIdx.x] : 0;
  t[threadIdx.x] = v;
  __syncthreads();
  for (int s = 1; s < 256; s <<= 1) {
    int u = (threadIdx.x >= s) ? t[threadIdx.x - s] : 0;
    __syncthreads();
    t[threadIdx.x] += u;
    __syncthreads();
  }
  if (threadIdx.x < NB_NODE) bsum[threadIdx.x] = t[threadIdx.x] - v;  // exclusive
}

__global__ void scan_write(const int* __restrict__ deg, const int* __restrict__ bsum,
                           int* __restrict__ rowp, int* __restrict__ cur) {
  __shared__ int t[256];
  int i = blockIdx.x * 256 + threadIdx.x;
  int v = (i < NN) ? deg[i] : 0;
  t[threadIdx.x] = v;
  __syncthreads();
  for (int s = 1; s < 256; s <<= 1) {
    int u = (threadIdx.x >= s) ? t[threadIdx.x - s] : 0;
    __syncthreads();
    t[threadIdx.x] += u;
    __syncthreads();
  }
  if (i < NN) {
    int ex = bsum[blockIdx.x] + t[threadIdx.x] - v;
    rowp[i] = ex;
    cur[i] = ex;
  }
}

__global__ void scatter_k(const int* __restrict__ src, const int* __restrict__ dst,
                          int* __restrict__ cur, int* __restrict__ ssrc) {
  int e = blockIdx.x * 256 + threadIdx.x;
  if (e >= NE) return;
  int d = dst[e];
  int pos = atomicAdd(&cur[d], 1);
  ssrc[pos] = src[e];
}

// ---------------- GAT projections ----------------

// fs12[n][32] = [fs1(16) | fs2(16)], fd12[n][32] = [fd1(16) | fd2(16)]
__global__ void proj12(const float* __restrict__ x,
                       const float* __restrict__ Ws1, const float* __restrict__ Wd1,
                       const float* __restrict__ Ws2, const float* __restrict__ Wd2,
                       float* __restrict__ fs12, float* __restrict__ fd12) {
  __shared__ float w[4][128];
  int tid = threadIdx.x;
  if (tid < 128) {
    w[0][tid] = Ws1[tid]; w[1][tid] = Wd1[tid];
    w[2][tid] = Ws2[tid]; w[3][tid] = Wd2[tid];
  }
  __syncthreads();
  int n = blockIdx.x * 256 + tid;
  if (n >= NN) return;
  float xi[8]; load8(x + (size_t)n * 8, xi);
  float o[16];
  #pragma unroll
  for (int m = 0; m < 4; ++m) {
    #pragma unroll
    for (int j = 0; j < 16; ++j) {
      float a = 0.f;
      #pragma unroll
      for (int i = 0; i < 8; ++i) a += xi[i] * w[m][i*16 + j];
      o[j] = a;
    }
    float* base = (m & 1) ? fd12 : fs12;
    store16(base + (size_t)n * 32 + (m >> 1) * 16, o);
  }
}

// ---------------- gathers (2 threads per node, shfl-combined) ----------------

// layers 1+2 + fused proj3: writes hinb cols 0..15 (h_att1), 32..39 (x), zeros 40..63;
// hdef1 fp32; fs3/fd3 fp32 (layer-3 projections).
__global__ __launch_bounds__(256) void gather12_p3(
    const int* __restrict__ rowp, const int* __restrict__ deg, const int* __restrict__ ssrc,
    const float* __restrict__ fs12, const float* __restrict__ fd12,
    const float* __restrict__ at1, const float* __restrict__ at2,
    const float* __restrict__ x,
    const float* __restrict__ re1, const float* __restrict__ bi1,
    const float* __restrict__ re2, const float* __restrict__ bi2,
    const float* __restrict__ Ws3, const float* __restrict__ Wd3,
    uint32_t* __restrict__ hinb32, float* __restrict__ hdef1,
    float* __restrict__ fs3, float* __restrict__ fd3) {
  __shared__ float r1[128], r2[128], ws3[256], wd3[256];
  __shared__ float atA[16], atB[16], b1s[16], b2s[16];
  int tid = threadIdx.x;
  if (tid < 128) { r1[tid] = re1[tid]; r2[tid] = re2[tid]; }
  ws3[tid] = Ws3[tid]; wd3[tid] = Wd3[tid];
  if (tid < 16) { atA[tid] = at1[tid]; atB[tid] = at2[tid];
                  b1s[tid] = bi1[tid]; b2s[tid] = bi2[tid]; }
  __syncthreads();
  int n = blockIdx.x * 128 + (tid >> 1);
  int half = tid & 1;
  bool alive = (n < NN);
  float fd[32];
  float acc[32];
  #pragma unroll
  for (int i = 0; i < 32; ++i) acc[i] = 0.f;
  float z[4] = {0.f, 0.f, 0.f, 0.f};
  int s0 = 0, d = 0;
  if (alive) {
    load16(fd12 + (size_t)n * 32, fd);
    load16(fd12 + (size_t)n * 32 + 16, fd + 16);
    s0 = rowp[n]; d = deg[n];
  }
  for (int i = half; i < d; i += 2) {
    int s = ssrc[s0 + i];
    const float* fp = fs12 + (size_t)s * 32;
    float fs[32];
    load16(fp, fs); load16(fp + 16, fs + 16);
    #pragma unroll
    for (int L = 0; L < 2; ++L) {
      #pragma unroll
      for (int h = 0; h < 2; ++h) {
        float sc = 0.f;
        #pragma unroll
        for (int d0 = 0; d0 < 8; ++d0) {
          int ix = L*16 + h*8 + d0;
          float e = fs[ix] + fd[ix];
          e = e > 0.f ? e : 0.2f * e;      // GATv2 leaky slope
          sc += e * (L ? atB[h*8+d0] : atA[h*8+d0]);
        }
        float p = __expf(sc);              // deferred-norm softmax
        z[L*2 + h] += p;
        #pragma unroll
        for (int d0 = 0; d0 < 8; ++d0) {
          int ix = L*16 + h*8 + d0;
          acc[ix] += p * fs[ix];
        }
      }
    }
  }
  // combine the pair (both lanes of a pair are same node; dead pairs are both dead)
  #pragma unroll
  for (int k = 0; k < 32; ++k) acc[k] += __shfl_xor(acc[k], 1);
  #pragma unroll
  for (int k = 0; k < 4; ++k) z[k] += __shfl_xor(z[k], 1);
  if (!alive) return;

  float xi[8]; load8(x + (size_t)n * 8, xi);
  uint32_t* row = hinb32 + (size_t)n * 32;   // 64 bf16 cols = 32 u32 words

  // layer 2 output (both lanes need it for fused proj3)
  float v2[16];
  #pragma unroll
  for (int j = 0; j < 16; ++j) {
    float r = 0.f;
    #pragma unroll
    for (int i = 0; i < 8; ++i) r += xi[i] * r2[i*16 + j];
    float zz = z[2 + (j >> 3)];
    float v = (zz > 0.f ? acc[16 + j] / zz : 0.f) + r + b2s[j];
    v2[j] = elu1(v);
  }

  if (half == 0) {
    // layer 1 -> hinb cols 0..15, x -> 32..39, zeros -> 40..63
    float v1[16];
    #pragma unroll
    for (int j = 0; j < 16; ++j) {
      float r = 0.f;
      #pragma unroll
      for (int i = 0; i < 8; ++i) r += xi[i] * r1[i*16 + j];
      float zz = z[j >> 3];
      float v = (zz > 0.f ? acc[j] / zz : 0.f) + r + b1s[j];
      v1[j] = elu1(v);
    }
    #pragma unroll
    for (int w = 0; w < 8; ++w) row[w] = pack2(v1[2*w], v1[2*w+1]);
    #pragma unroll
    for (int w = 0; w < 4; ++w) row[16 + w] = pack2(xi[2*w], xi[2*w+1]);
    #pragma unroll
    for (int w = 20; w < 32; ++w) row[w] = 0u;
  } else {
    store16(hdef1 + (size_t)n * 16, v2);
  }

  // fused proj3: this lane computes cols j0..j0+7 of fs3/fd3
  int j0 = half * 8;
  float o1[8], o2[8];
  #pragma unroll
  for (int j = 0; j < 8; ++j) {
    float a1 = 0.f, a2 = 0.f;
    #pragma unroll
    for (int i = 0; i < 16; ++i) {
      a1 += v2[i] * ws3[i*16 + j0 + j];
      a2 += v2[i] * wd3[i*16 + j0 + j];
    }
    o1[j] = a1; o2[j] = a2;
  }
  store8(fs3 + (size_t)n * 16 + j0, o1);
  store8(fd3 + (size_t)n * 16 + j0, o2);
}

// layer 3: identity residual; writes hinb cols 16..31
__global__ __launch_bounds__(256) void gather3_k(
    const int* __restrict__ rowp, const int* __restrict__ deg, const int* __restrict__ ssrc,
    const float* __restrict__ fs3, const float* __restrict__ fd3,
    const float* __restrict__ at3, const float* __restrict__ bi3,
    const float* __restrict__ hdef1, uint32_t* __restrict__ hinb32) {
  __shared__ float at[16], b3[16];
  int tid = threadIdx.x;
  if (tid < 16) { at[tid] = at3[tid]; b3[tid] = bi3[tid]; }
  __syncthreads();
  int n = blockIdx.x * 128 + (tid >> 1);
  int half = tid & 1;
  bool alive = (n < NN);
  float fd[16];
  float acc[16];
  #pragma unroll
  for (int i = 0; i < 16; ++i) acc[i] = 0.f;
  float z[2] = {0.f, 0.f};
  int s0 = 0, d = 0;
  if (alive) {
    load16(fd3 + (size_t)n * 16, fd);
    s0 = rowp[n]; d = deg[n];
  }
  for (int i = half; i < d; i += 2) {
    int s = ssrc[s0 + i];
    float fs[16];
    load16(fs3 + (size_t)s * 16, fs);
    #pragma unroll
    for (int h = 0; h < 2; ++h) {
      float sc = 0.f;
      #pragma unroll
      for (int d0 = 0; d0 < 8; ++d0) {
        int ix = h*8 + d0;
        float e = fs[ix] + fd[ix];
        e = e > 0.f ? e : 0.2f * e;
        sc += e * at[ix];
      }
      float p = __expf(sc);
      z[h] += p;
      #pragma unroll
      for (int d0 = 0; d0 < 8; ++d0) {
        int ix = h*8 + d0;
        acc[ix] += p * fs[ix];
      }
    }
  }
  #pragma unroll
  for (int k = 0; k < 16; ++k) acc[k] += __shfl_xor(acc[k], 1);
  #pragma unroll
  for (int k = 0; k < 2; ++k) z[k] += __shfl_xor(z[k], 1);
  if (!alive) return;

  int j0 = half * 8;
  float hd[8]; load8(hdef1 + (size_t)n * 16 + j0, hd);
  uint32_t* row = hinb32 + (size_t)n * 32;
  float v[8];
  float zz = z[half];
  #pragma unroll
  for (int j = 0; j < 8; ++j) {
    float o = (zz > 0.f ? acc[j0 + j] / zz : 0.f) + hd[j] + b3[j0 + j];
    v[j] = elu1(o);
  }
  #pragma unroll
  for (int w = 0; w < 4; ++w) row[8 + half*4 + w] = pack2(v[2*w], v[2*w+1]);
}

// ---------------- MLP part (bf16 MFMA) ----------------

__global__ void transpose_to_bf16(const float* __restrict__ in, uint16_t* __restrict__ outT,
                                  int R, int C, int ldout) {
  __shared__ float t[32][33];
  int rb = blockIdx.x * 32, cb = blockIdx.y * 32;
  int tx = threadIdx.x & 31, ty = threadIdx.x >> 5;
  #pragma unroll
  for (int y = ty; y < 32; y += 8) {
    int r = rb + y, c = cb + tx;
    t[y][tx] = (r < R && c < C) ? in[(size_t)r * C + c] : 0.f;
  }
  __syncthreads();
  #pragma unroll
  for (int y = ty; y < 32; y += 8) {
    int c = cb + y, r = rb + tx;
    if (c < C && r < R) outT[(size_t)c * ldout + r] = f2bf(t[tx][y]);
  }
}

__device__ __forceinline__ void gload16(const void* g, void* l) {
  __builtin_amdgcn_global_load_lds((const __attribute__((address_space(1))) unsigned int*)g,
                                   (__attribute__((address_space(3))) unsigned int*)l, 16, 0, 0);
}

// BK=64, 128x128 tile, 4 waves 2x2, 64x64 per wave.
// LDS tiles [128][64] bf16, XOR-swizzled: 16B chunk kc of row r holds global chunk kc^(r&7).
// (linear LDS dest for global_load_lds + inverse-swizzled global source + swizzled ds_read)
template <bool OUT_BF16>
__device__ __forceinline__ void gemm_core(const uint16_t* __restrict__ A,
                                          const uint16_t* __restrict__ Bt,
                                          const float* __restrict__ bias,
                                          void* __restrict__ Cout,
                                          int K, int ldC, int Nreal, float slope,
                                          int bn, int bm) {
  __shared__ __align__(16) uint16_t As[128 * 64];
  __shared__ __align__(16) uint16_t Bs[128 * 64];
  const int tid = threadIdx.x;
  const int lane = tid & 63;
  const int wave = tid >> 6;
  const int wm = (wave >> 1) * 64;
  const int wn = (wave & 1) * 64;
  const long nt = (long)bn * 128;
  const long mt = (long)bm * 128;

  // staging: chunk c = tid + 256*s (s=0..3); row=c>>3 (=r0+32s), kc=c&7 (s-invariant)
  const int r0 = tid >> 3;
  const int kc = tid & 7;
  const int skc = kc ^ (r0 & 7);          // r0&7 == row&7 for all s (rows step by 32)
  const uint16_t* Ag0 = A  + (mt + r0) * (long)K + skc * 8;
  const uint16_t* Bg0 = Bt + (nt + r0) * (long)K + skc * 8;
  uint16_t* Al0 = As + tid * 8;
  uint16_t* Bl0 = Bs + tid * 8;
  const long gstep = (long)32 * K;        // 32 rows per staging step

  const int lr = lane & 15, kg = lane >> 4;
  const int x7 = lr & 7;
  const int sw0 = (kg ^ x7) * 8;          // ks=0: chunks 0..3 swizzled
  const int sw1 = ((4 + kg) ^ x7) * 8;    // ks=1: chunks 4..7 swizzled

  f32x4 acc[4][4] = {};

  for (int kk = 0; kk < K; kk += 64) {
    #pragma unroll
    for (int s = 0; s < 4; ++s) gload16(Ag0 + gstep*s + kk, Al0 + 2048*s);
    #pragma unroll
    for (int s = 0; s < 4; ++s) gload16(Bg0 + gstep*s + kk, Bl0 + 2048*s);
    __syncthreads();
    s16x8 b0[4], b1[4];
    #pragma unroll
    for (int j = 0; j < 4; ++j) {
      int rb = (wn + j*16 + lr) * 64;
      b0[j] = *(const s16x8*)(Bs + rb + sw0);
      b1[j] = *(const s16x8*)(Bs + rb + sw1);
    }
    #pragma unroll
    for (int i = 0; i < 4; ++i) {
      int rb = (wm + i*16 + lr) * 64;
      s16x8 a0 = *(const s16x8*)(As + rb + sw0);
      s16x8 a1 = *(const s16x8*)(As + rb + sw1);
      #pragma unroll
      for (int j = 0; j < 4; ++j) {
        acc[i][j] = __builtin_amdgcn_mfma_f32_16x16x32_bf16(a0, b0[j], acc[i][j], 0, 0, 0);
        acc[i][j] = __builtin_amdgcn_mfma_f32_16x16x32_bf16(a1, b1[j], acc[i][j], 0, 0, 0);
      }
    }
    __syncthreads();
  }

  // C/D layout (verified m89/m91): col = lane&15, row = (lane>>4)*4 + t
  const int cr = (lane >> 4) * 4;
  const int cc = lane & 15;
  #pragma unroll
  for (int j = 0; j < 4; ++j) {
    const long col = nt + wn + j*16 + cc;
    if (col >= Nreal) continue;
    const float bv = bias[col];
    #pragma unroll
    for (int i = 0; i < 4; ++i) {
      #pragma unroll
      for (int t = 0; t < 4; ++t) {
        const long row = mt + wm + i*16 + cr + t;
        float v = acc[i][j][t] + bv;
        v = v > 0.f ? v : slope * v;
        if (OUT_BF16) ((uint16_t*)Cout)[row * (long)ldC + col] = f2bf(v);
        else          ((float*)Cout)[row * (long)ldC + col] = v;
      }
    }
  }
}

__global__ __launch_bounds__(256) void gemm_l1(const uint16_t* __restrict__ A,
                                               const uint16_t* __restrict__ Bt,
                                               const float* __restrict__ bias,
                                               void* __restrict__ Cout) {
  gemm_core<true>(A, Bt, bias, Cout, 64, 1600, 1600, 0.01f, blockIdx.x, blockIdx.y);
}

// 1-D grid, m204 bijective XCD-chunked swizzle; n fast within a chunk (A-panel L2 reuse)
__global__ __launch_bounds__(256) void gemm_l2(const uint16_t* __restrict__ A,
                                               const uint16_t* __restrict__ Bt,
                                               const float* __restrict__ bias,
                                               void* __restrict__ Cout) {
  const int nwg = gridDim.x;
  const int q = nwg >> 3, r = nwg & 7;
  const int xcd = blockIdx.x & 7, j = blockIdx.x >> 3;
  const int L = (xcd < r ? xcd * (q + 1) : r * (q + 1) + (xcd - r) * q) + j;
  gemm_core<true>(A, Bt, bias, Cout, 1600, 1600, 1600, 0.01f, L % 13, L / 13);
}

__global__ __launch_bounds__(256) void gemm_l3(const uint16_t* __restrict__ A,
                                               const uint16_t* __restrict__ Bt,
                                               const float* __restrict__ bias,
                                               void* __restrict__ Cout) {
  gemm_core<false>(A, Bt, bias, Cout, 1600, 40, 40, 0.01f, 0, blockIdx.y);
}

__global__ void mlp4(const float* __restrict__ h3, const float* __restrict__ W4,
                     const float* __restrict__ b4, float* __restrict__ out,
                     int m0, int rows) {
  int r = blockIdx.x * 256 + threadIdx.x;
  if (r >= rows) return;
  const float* t = h3 + (size_t)r * 40;
  float a = 0.f;
  #pragma unroll
  for (int k = 0; k < 40; k += 4) {
    float4 tv = *(const float4*)(t + k);
    float4 wv = *(const float4*)(W4 + k);
    a += tv.x*wv.x + tv.y*wv.y + tv.z*wv.z + tv.w*wv.w;
  }
  a += b4[0];
  out[m0 + r] = 1.f / (1.f + __expf(-a));
}

// ---------------- host ----------------

extern "C" void kernel_launch(void* const* d_in, const int* in_sizes, int n_in,
                              void* d_out, int out_size, void* d_ws, size_t ws_size,
                              hipStream_t stream) {
  const float* x   = (const float*)d_in[0];
  const int*   src = (const int*)d_in[1];
  const int*   dst = (const int*)d_in[2];
  const float* Ws1 = (const float*)d_in[3];
  const float* Wd1 = (const float*)d_in[4];
  const float* at1 = (const float*)d_in[5];
  const float* bi1 = (const float*)d_in[6];
  const float* re1 = (const float*)d_in[7];
  const float* Ws2 = (const float*)d_in[8];
  const float* Wd2 = (const float*)d_in[9];
  const float* at2 = (const float*)d_in[10];
  const float* bi2 = (const float*)d_in[11];
  const float* re2 = (const float*)d_in[12];
  const float* Ws3 = (const float*)d_in[13];
  const float* Wd3 = (const float*)d_in[14];
  const float* at3 = (const float*)d_in[15];
  const float* bi3 = (const float*)d_in[16];
  const float* W1  = (const float*)d_in[17];
  const float* b1  = (const float*)d_in[18];
  const float* W2  = (const float*)d_in[19];
  const float* b2  = (const float*)d_in[20];
  const float* W3  = (const float*)d_in[21];
  const float* b3  = (const float*)d_in[22];
  const float* W4  = (const float*)d_in[23];
  const float* b4  = (const float*)d_in[24];
  float* out = (float*)d_out;

  char* ws = (char*)d_ws;
  size_t off = 0;
  auto alloc = [&](size_t bytes) -> void* {
    off = (off + 255) & ~(size_t)255;
    void* p = ws + off;
    off += bytes;
    return p;
  };
  // CSR
  int* deg  = (int*)alloc((size_t)NN * 4);
  int* rowp = (int*)alloc((size_t)NN * 4);
  int* cur  = (int*)alloc((size_t)NN * 4);
  int* bsum = (int*)alloc((size_t)NB_NODE * 4);
  int* ssrc = (int*)alloc((size_t)NE * 4);
  // GAT features
  float* fs12  = (float*)alloc((size_t)NN * 32 * 4);
  float* fd12  = (float*)alloc((size_t)NN * 32 * 4);
  float* fs3   = (float*)alloc((size_t)NN * 16 * 4);
  float* fd3   = (float*)alloc((size_t)NN * 16 * 4);
  float* hdef1 = (float*)alloc((size_t)NN * 16 * 4);
  // MLP
  uint16_t* hinb = (uint16_t*)alloc((size_t)60032 * 64 * 2);
  uint16_t* W1T  = (uint16_t*)alloc((size_t)1664 * 64 * 2);
  uint16_t* W2T  = (uint16_t*)alloc((size_t)1664 * 1600 * 2);
  uint16_t* W3T  = (uint16_t*)alloc((size_t)128 * 1600 * 2);

  size_t fixed_end = (off + 255) & ~(size_t)255;
  size_t avail = (ws_size > fixed_end + 4096) ? (ws_size - fixed_end - 4096) : 0;
  long mc = (long)(avail / 6560);
  mc = (mc / 128) * 128;
  if (mc > 60032) mc = 60032;
  if (mc < 128) mc = 128;
  uint16_t* h1c = (uint16_t*)alloc((size_t)mc * 1600 * 2);
  uint16_t* h2c = (uint16_t*)alloc((size_t)mc * 1600 * 2);
  float*    h3c = (float*)alloc((size_t)mc * 40 * 4);

  hipMemsetAsync(deg, 0, (size_t)NN * 4, stream);
  hipMemsetAsync(hinb + (size_t)60000 * 64, 0, (size_t)32 * 64 * 2, stream);  // pad rows
  hipMemsetAsync(W1T, 0, (size_t)1664 * 64 * 2, stream);
  hipMemsetAsync(W3T, 0, (size_t)128 * 1600 * 2, stream);
  hipMemsetAsync(W2T + (size_t)1600 * 1600, 0, (size_t)64 * 1600 * 2, stream);

  const int EB = (NE + 255) / 256;
  // CSR build
  hist_k<<<EB, 256, 0, stream>>>(dst, deg);
  scan_block<<<NB_NODE, 256, 0, stream>>>(deg, bsum);
  scan_tops<<<1, 256, 0, stream>>>(bsum);
  scan_write<<<NB_NODE, 256, 0, stream>>>(deg, bsum, rowp, cur);
  scatter_k<<<EB, 256, 0, stream>>>(src, dst, cur, ssrc);

  // weight prep
  transpose_to_bf16<<<dim3(2, 50), 256, 0, stream>>>(W1, W1T, 40, 1600, 64);
  transpose_to_bf16<<<dim3(50, 50), 256, 0, stream>>>(W2, W2T, 1600, 1600, 1600);
  transpose_to_bf16<<<dim3(50, 2), 256, 0, stream>>>(W3, W3T, 1600, 40, 1600);

  // GAT
  proj12<<<NB_NODE, 256, 0, stream>>>(x, Ws1, Wd1, Ws2, Wd2, fs12, fd12);
  gather12_p3<<<NB_PAIR, 256, 0, stream>>>(rowp, deg, ssrc, fs12, fd12, at1, at2,
                                           x, re1, bi1, re2, bi2, Ws3, Wd3,
                                           (uint32_t*)hinb, hdef1, fs3, fd3);
  gather3_k<<<NB_PAIR, 256, 0, stream>>>(rowp, deg, ssrc, fs3, fd3, at3, bi3,
                                         hdef1, (uint32_t*)hinb);

  // MLP
  for (long m0 = 0; m0 < NN; m0 += mc) {
    long rows_real = NN - m0; if (rows_real > mc) rows_real = mc;
    long rows_pad = (rows_real + 127) & ~127L;
    unsigned mtiles = (unsigned)(rows_pad / 128);
    gemm_l1<<<dim3(13, mtiles), 256, 0, stream>>>(hinb + m0 * 64, W1T, b1, h1c);
    gemm_l2<<<13 * mtiles, 256, 0, stream>>>(h1c, W2T, b2, h2c);
    gemm_l3<<<dim3(1, mtiles), 256, 0, stream>>>(h2c, W3T, b3, h3c);
    mlp4<<<(unsigned)((rows_real + 255) / 256), 256, 0, stream>>>(h3c, W4, b4, out, (int)m0, (int)rows_real);
  }
}